// Round 1
// baseline (679.547 us; speedup 1.0000x reference)
//
#include <hip/hip_runtime.h>
#include <hip/hip_bf16.h>
#include <cstdint>

#define NEXP 8
#define NTOK 256
#define NSLOT 512   // NTOK * TOPK
#define HD 2048
#define ID 1024

// ---------------------------------------------------------------------------
// Routing: build per-expert slot lists. slot s = t*2 + k.
// ---------------------------------------------------------------------------
__global__ __launch_bounds__(256) void route_k(const int* __restrict__ ids,
                                               int* __restrict__ counts,
                                               int* __restrict__ slots) {
  int tid = threadIdx.x;
  if (tid < NEXP) counts[tid] = 0;
  __syncthreads();
  for (int s = tid; s < NSLOT; s += 256) {
    int e = ids[s];
    int pos = atomicAdd(&counts[e], 1);
    slots[e * NSLOT + pos] = s;
  }
}

// ---------------------------------------------------------------------------
// Grouped GEMM with fused block-128 dequant.
// C[slot, n] = sum_k A[slot>>ashift, k] * B[e, n, k] * Sc[e, n/128, k/128]
// Tile: BM=128 slots, BN=64 n-rows, BK=32. 256 thr, 8x4 micro-tile.
// grid = (N/64, 4, NEXP); blocks with mbase >= cnt exit.
// ---------------------------------------------------------------------------
__global__ __launch_bounds__(256) void moe_gemm(
    const float* __restrict__ A, int lda, int ashift,
    const float* __restrict__ B, int64_t bstride, int K,
    const float* __restrict__ Sc, int sstride_e, int sstride_n,
    float* __restrict__ C, int ldc,
    const int* __restrict__ counts, const int* __restrict__ slots) {
  const int e = blockIdx.z;
  const int cnt = counts[e];
  const int mbase = blockIdx.y * 128;
  if (mbase >= cnt) return;
  const int n0 = blockIdx.x * 64;
  const float* Be = B + (int64_t)e * bstride;
  const float* Se = Sc + e * sstride_e;

  __shared__ float As[32][132];  // [BK][BM+4] transposed, padded (16B-aligned rows)
  __shared__ float Bs[32][68];   // [BK][BN+4]

  const int tid = threadIdx.x;
  const int r  = tid >> 3;        // 0..31 staging row
  const int kq = (tid & 7) << 2;  // 0,4,...,28 staging k-offset

  const int* sl = slots + e * NSLOT;
  const float* ap[4];
#pragma unroll
  for (int q = 0; q < 4; ++q) {
    int m = mbase + r + q * 32;
    m = m < cnt ? m : cnt - 1;          // clamp: redundant load, write-guarded later
    ap[q] = A + (int64_t)(sl[m] >> ashift) * lda + kq;
  }
  const float* bp0 = Be + (int64_t)(n0 + r) * K + kq;
  const float* bp1 = Be + (int64_t)(n0 + r + 32) * K + kq;
  const int sn0 = (n0 + r) >> 7;
  const int sn1 = (n0 + r + 32) >> 7;

  float acc[8][4];
#pragma unroll
  for (int i = 0; i < 8; ++i)
#pragma unroll
    for (int j = 0; j < 4; ++j) acc[i][j] = 0.f;

  const int tx = tid & 15;  // n: 4 cols at tx*4
  const int ty = tid >> 4;  // m: 8 rows at ty*8

  float4 av[4], bv[2];
  {
    float s0 = Se[sn0 * sstride_n];
    float s1 = Se[sn1 * sstride_n];
#pragma unroll
    for (int q = 0; q < 4; ++q) av[q] = *(const float4*)(ap[q]);
    bv[0] = *(const float4*)(bp0);
    bv[1] = *(const float4*)(bp1);
    bv[0].x *= s0; bv[0].y *= s0; bv[0].z *= s0; bv[0].w *= s0;
    bv[1].x *= s1; bv[1].y *= s1; bv[1].z *= s1; bv[1].w *= s1;
  }

  for (int k0 = 0; k0 < K; k0 += 32) {
    __syncthreads();
#pragma unroll
    for (int j = 0; j < 4; ++j) {
      As[kq + j][r]      = ((const float*)&av[0])[j];
      As[kq + j][r + 32] = ((const float*)&av[1])[j];
      As[kq + j][r + 64] = ((const float*)&av[2])[j];
      As[kq + j][r + 96] = ((const float*)&av[3])[j];
      Bs[kq + j][r]      = ((const float*)&bv[0])[j];
      Bs[kq + j][r + 32] = ((const float*)&bv[1])[j];
    }
    __syncthreads();
    if (k0 + 32 < K) {  // software prefetch next K-tile into registers
      const int kn = k0 + 32;
      const int kb = (kn + kq) >> 7;
      float s0 = Se[sn0 * sstride_n + kb];
      float s1 = Se[sn1 * sstride_n + kb];
#pragma unroll
      for (int q = 0; q < 4; ++q) av[q] = *(const float4*)(ap[q] + kn);
      bv[0] = *(const float4*)(bp0 + kn);
      bv[1] = *(const float4*)(bp1 + kn);
      bv[0].x *= s0; bv[0].y *= s0; bv[0].z *= s0; bv[0].w *= s0;
      bv[1].x *= s1; bv[1].y *= s1; bv[1].z *= s1; bv[1].w *= s1;
    }
#pragma unroll
    for (int k = 0; k < 32; ++k) {
      const float4 a0 = *(const float4*)(&As[k][ty * 8]);
      const float4 a1 = *(const float4*)(&As[k][ty * 8 + 4]);
      const float4 b  = *(const float4*)(&Bs[k][tx * 4]);
      const float am[8] = {a0.x, a0.y, a0.z, a0.w, a1.x, a1.y, a1.z, a1.w};
      const float bn[4] = {b.x, b.y, b.z, b.w};
#pragma unroll
      for (int i = 0; i < 8; ++i)
#pragma unroll
        for (int j = 0; j < 4; ++j) acc[i][j] = fmaf(am[i], bn[j], acc[i][j]);
    }
  }

#pragma unroll
  for (int i = 0; i < 8; ++i) {
    int m = mbase + ty * 8 + i;
    if (m < cnt) {
      int slot = sl[m];
      float4 v = make_float4(acc[i][0], acc[i][1], acc[i][2], acc[i][3]);
      *(float4*)(C + (int64_t)slot * ldc + n0 + tx * 4) = v;
    }
  }
}

// ---------------------------------------------------------------------------
// act[s][i] = silu(gu[s][i]) * gu[s][I+i]
// ---------------------------------------------------------------------------
__global__ __launch_bounds__(256) void act_k(const float* __restrict__ gu,
                                             float* __restrict__ act) {
  int idx = blockIdx.x * 256 + threadIdx.x;   // < NSLOT * ID/4 = 131072
  int s  = idx >> 8;
  int i4 = (idx & 255) << 2;
  const float4 g = *(const float4*)(gu + (int64_t)s * (2 * ID) + i4);
  const float4 u = *(const float4*)(gu + (int64_t)s * (2 * ID) + ID + i4);
  float4 r;
  r.x = g.x / (1.f + expf(-g.x)) * u.x;
  r.y = g.y / (1.f + expf(-g.y)) * u.y;
  r.z = g.z / (1.f + expf(-g.z)) * u.z;
  r.w = g.w / (1.f + expf(-g.w)) * u.w;
  *(float4*)(act + (int64_t)s * ID + i4) = r;
}

// ---------------------------------------------------------------------------
// out[t][h] = w[t,0]*y[2t][h] + w[t,1]*y[2t+1][h]
// ---------------------------------------------------------------------------
__global__ __launch_bounds__(256) void combine_k(const float* __restrict__ y,
                                                 const float* __restrict__ wts,
                                                 float* __restrict__ out) {
  int idx = blockIdx.x * 256 + threadIdx.x;   // < NTOK * HD/4 = 131072
  int t  = idx >> 9;
  int h4 = (idx & 511) << 2;
  float w0 = wts[t * 2], w1 = wts[t * 2 + 1];
  const float4 y0 = *(const float4*)(y + (int64_t)(2 * t) * HD + h4);
  const float4 y1 = *(const float4*)(y + (int64_t)(2 * t + 1) * HD + h4);
  float4 r;
  r.x = w0 * y0.x + w1 * y1.x;
  r.y = w0 * y0.y + w1 * y1.y;
  r.z = w0 * y0.z + w1 * y1.z;
  r.w = w0 * y0.w + w1 * y1.w;
  *(float4*)(out + (int64_t)t * HD + h4) = r;
}

extern "C" void kernel_launch(void* const* d_in, const int* in_sizes, int n_in,
                              void* d_out, int out_size, void* d_ws, size_t ws_size,
                              hipStream_t stream) {
  const float* x   = (const float*)d_in[0];
  const int*   ids = (const int*)d_in[1];
  const float* wts = (const float*)d_in[2];
  const float* w13 = (const float*)d_in[3];
  const float* s13 = (const float*)d_in[4];
  const float* w2  = (const float*)d_in[5];
  const float* s2  = (const float*)d_in[6];
  float* out = (float*)d_out;

  char* ws = (char*)d_ws;
  int* counts = (int*)ws;                                 // 32 B
  int* slots  = (int*)(ws + 64);                          // 16 KiB
  float* gu   = (float*)(ws + 32768);                     // 4 MiB (512 x 2048)
  float* act  = (float*)(ws + 32768 + (4u << 20));        // 2 MiB (512 x 1024)
  float* y    = (float*)(ws + 32768 + (6u << 20));        // 4 MiB (512 x 2048)

  route_k<<<1, 256, 0, stream>>>(ids, counts, slots);

  // GEMM1: gu[slot, n] over n in [0, 2I), K = H
  moe_gemm<<<dim3(32, 4, NEXP), 256, 0, stream>>>(
      x, HD, 1,
      w13, (int64_t)(2 * ID) * HD, HD,
      s13, (2 * ID / 128) * (HD / 128), HD / 128,
      gu, 2 * ID, counts, slots);

  act_k<<<512, 256, 0, stream>>>(gu, act);

  // GEMM2: y[slot, h] over h in [0, H), K = I
  moe_gemm<<<dim3(32, 4, NEXP), 256, 0, stream>>>(
      act, ID, 0,
      w2, (int64_t)HD * ID, ID,
      s2, (HD / 128) * (ID / 128), ID / 128,
      y, HD, counts, slots);

  combine_k<<<512, 256, 0, stream>>>(y, wts, out);
}

// Round 2
// 337.827 us; speedup vs baseline: 2.0115x; 2.0115x over previous
//
#include <hip/hip_runtime.h>
#include <cstdint>

#define NEXP 8
#define NTOK 256
#define NSLOT 512   // NTOK * TOPK
#define HD 2048
#define ID 1024

typedef short bf16x8 __attribute__((ext_vector_type(8)));
typedef float f32x4  __attribute__((ext_vector_type(4)));

// ---------------------------------------------------------------------------
// Routing: per-expert slot lists. slot s = t*2 + k.
// ---------------------------------------------------------------------------
__global__ __launch_bounds__(256) void route_k(const int* __restrict__ ids,
                                               int* __restrict__ counts,
                                               int* __restrict__ slots) {
  int tid = threadIdx.x;
  if (tid < NEXP) counts[tid] = 0;
  __syncthreads();
  for (int s = tid; s < NSLOT; s += 256) {
    int e = ids[s];
    int pos = atomicAdd(&counts[e], 1);
    slots[e * NSLOT + pos] = s;
  }
}

// split fp32 -> (hi, lo) bf16 pair; hi = truncation, lo = rne(f - hi).
// Reconstruction error ~2^-16 relative (dropped lo*lo term) — below fp32 path.
__device__ __forceinline__ void split4(float x, float y, float z, float w,
                                       uint2& hi, uint2& lo) {
  uint32_t u0 = __float_as_uint(x), u1 = __float_as_uint(y),
           u2 = __float_as_uint(z), u3 = __float_as_uint(w);
  uint32_t h0 = u0 & 0xFFFF0000u, h1 = u1 & 0xFFFF0000u;
  uint32_t h2 = u2 & 0xFFFF0000u, h3 = u3 & 0xFFFF0000u;
  hi.x = (u0 >> 16) | h1;
  hi.y = (u2 >> 16) | h3;
  float l0 = x - __uint_as_float(h0), l1 = y - __uint_as_float(h1);
  float l2 = z - __uint_as_float(h2), l3 = w - __uint_as_float(h3);
  lo.x = (__float_as_uint(l0) >> 16) | (__float_as_uint(l1) & 0xFFFF0000u);
  lo.y = (__float_as_uint(l2) >> 16) | (__float_as_uint(l3) & 0xFFFF0000u);
}

// ---------------------------------------------------------------------------
// Grouped GEMM, split-bf16 MFMA, fused block-128 dequant.
// C[slot, n] = sum_k A[slot>>ASHIFT, k] * B[e, n, k] * Sc[e, n/128, k/128]
// Tile BM=64 x BN=64 x BK=32. 4 waves (2x2), 32x32 out/wave.
// Double-buffered LDS + 2-deep register prefetch.
// ---------------------------------------------------------------------------
template <int K, int ASHIFT>
__global__ __launch_bounds__(256, 2) void moe_gemm_mfma(
    const float* __restrict__ A, int lda,
    const float* __restrict__ B, int64_t bstride,
    const float* __restrict__ Sc, int sstride_e, int sstride_n,
    float* __restrict__ C, int ldc,
    const int* __restrict__ counts, const int* __restrict__ slots) {
  constexpr int NT = K / 32;
  const int e = blockIdx.z;
  const int cnt = counts[e];
  const int mbase = blockIdx.y * 64;
  if (mbase >= cnt) return;
  const int n0 = blockIdx.x * 64;

  __shared__ ushort Ah[2][64][32], Al[2][64][32];
  __shared__ ushort Bh[2][64][32], Bl[2][64][32];
  __shared__ int s_slots[64];

  const int tid = threadIdx.x;
  const int lane = tid & 63;
  const int wave = tid >> 6;
  const int wm = wave >> 1;   // 0..1 : 32-row strip
  const int wn = wave & 1;    // 0..1 : 32-col strip

  const int* sl = slots + e * NSLOT;
  if (tid < 64) {
    int m = mbase + tid;
    s_slots[tid] = sl[m < cnt ? m : cnt - 1];
  }

  const int rs = tid >> 3;         // 0..31 staging row
  const int c4 = (tid & 7) << 2;   // 0..28 staging k (floats)

  int ma0 = mbase + rs;      ma0 = ma0 < cnt ? ma0 : cnt - 1;
  int ma1 = mbase + 32 + rs; ma1 = ma1 < cnt ? ma1 : cnt - 1;
  const float* ap0 = A + (int64_t)(sl[ma0] >> ASHIFT) * lda + c4;
  const float* ap1 = A + (int64_t)(sl[ma1] >> ASHIFT) * lda + c4;
  const float* Be  = B + (int64_t)e * bstride;
  const float* bp0 = Be + (int64_t)(n0 + rs) * K + c4;
  const float* bp1 = Be + (int64_t)(n0 + 32 + rs) * K + c4;
  const float* Se  = Sc + e * sstride_e + (n0 >> 7) * sstride_n;

  f32x4 acc[2][2] = {};

  // two register prefetch sets
  float4 A0a, A1a, B0a, B1a;
  float4 A0b, A1b, B0b, B1b;

#define GLOAD(S, t)                                  \
  {                                                  \
    const int k0_ = (t) * 32;                        \
    A0##S = *(const float4*)(ap0 + k0_);             \
    A1##S = *(const float4*)(ap1 + k0_);             \
    B0##S = *(const float4*)(bp0 + k0_);             \
    B1##S = *(const float4*)(bp1 + k0_);             \
  }

  auto stage = [&](int buf, int tt, const float4& a0, const float4& a1,
                   const float4& b0, const float4& b1) {
    const float s = Se[tt >> 2];   // one scale block per (tile, k-step)
    uint2 h, l;
    split4(a0.x, a0.y, a0.z, a0.w, h, l);
    *(uint2*)&Ah[buf][rs][c4] = h;       *(uint2*)&Al[buf][rs][c4] = l;
    split4(a1.x, a1.y, a1.z, a1.w, h, l);
    *(uint2*)&Ah[buf][rs + 32][c4] = h;  *(uint2*)&Al[buf][rs + 32][c4] = l;
    split4(b0.x * s, b0.y * s, b0.z * s, b0.w * s, h, l);
    *(uint2*)&Bh[buf][rs][c4] = h;       *(uint2*)&Bl[buf][rs][c4] = l;
    split4(b1.x * s, b1.y * s, b1.z * s, b1.w * s, h, l);
    *(uint2*)&Bh[buf][rs + 32][c4] = h;  *(uint2*)&Bl[buf][rs + 32][c4] = l;
  };

  auto do_mfma = [&](int buf) {
    if (mbase + (wm << 5) >= cnt) return;   // wave-uniform skip
    const int k8 = (lane >> 4) << 3;
    const int ar = (wm << 5) + (lane & 15);
    const int br = (wn << 5) + (lane & 15);
    bf16x8 ah[2], al2[2], bh[2], bl2[2];
#pragma unroll
    for (int i = 0; i < 2; ++i) {
      ah[i]  = *(const bf16x8*)&Ah[buf][ar + i * 16][k8];
      al2[i] = *(const bf16x8*)&Al[buf][ar + i * 16][k8];
      bh[i]  = *(const bf16x8*)&Bh[buf][br + i * 16][k8];
      bl2[i] = *(const bf16x8*)&Bl[buf][br + i * 16][k8];
    }
#pragma unroll
    for (int mf = 0; mf < 2; ++mf)
#pragma unroll
      for (int nf = 0; nf < 2; ++nf) {
        acc[mf][nf] = __builtin_amdgcn_mfma_f32_16x16x32_bf16(ah[mf],  bh[nf],  acc[mf][nf], 0, 0, 0);
        acc[mf][nf] = __builtin_amdgcn_mfma_f32_16x16x32_bf16(ah[mf],  bl2[nf], acc[mf][nf], 0, 0, 0);
        acc[mf][nf] = __builtin_amdgcn_mfma_f32_16x16x32_bf16(al2[mf], bh[nf],  acc[mf][nf], 0, 0, 0);
      }
  };

  GLOAD(a, 0)
  GLOAD(b, 1)
  stage(0, 0, A0a, A1a, B0a, B1a);
  __syncthreads();

  for (int t = 0; t < NT; t += 2) {
    if (t + 2 < NT) GLOAD(a, t + 2)
    do_mfma(0);
    stage(1, t + 1, A0b, A1b, B0b, B1b);
    __syncthreads();
    if (t + 3 < NT) GLOAD(b, t + 3)
    do_mfma(1);
    if (t + 2 < NT) stage(0, t + 2, A0a, A1a, B0a, B1a);
    __syncthreads();
  }
#undef GLOAD

  // epilogue: C/D layout col = lane&15, row = (lane>>4)*4 + reg  [m89]
#pragma unroll
  for (int mf = 0; mf < 2; ++mf) {
#pragma unroll
    for (int nf = 0; nf < 2; ++nf) {
      const int rbase = (wm << 5) + (mf << 4) + ((lane >> 4) << 2);
      const int col = n0 + (wn << 5) + (nf << 4) + (lane & 15);
#pragma unroll
      for (int r = 0; r < 4; ++r) {
        const int row = rbase + r;
        if (mbase + row < cnt)
          C[(int64_t)s_slots[row] * ldc + col] = acc[mf][nf][r];
      }
    }
  }
}

// ---------------------------------------------------------------------------
// act[s][i] = silu(gu[s][i]) * gu[s][I+i]
// ---------------------------------------------------------------------------
__global__ __launch_bounds__(256) void act_k(const float* __restrict__ gu,
                                             float* __restrict__ act) {
  int idx = blockIdx.x * 256 + threadIdx.x;   // < NSLOT * ID/4 = 131072
  int s  = idx >> 8;
  int i4 = (idx & 255) << 2;
  const float4 g = *(const float4*)(gu + (int64_t)s * (2 * ID) + i4);
  const float4 u = *(const float4*)(gu + (int64_t)s * (2 * ID) + ID + i4);
  float4 r;
  r.x = g.x / (1.f + expf(-g.x)) * u.x;
  r.y = g.y / (1.f + expf(-g.y)) * u.y;
  r.z = g.z / (1.f + expf(-g.z)) * u.z;
  r.w = g.w / (1.f + expf(-g.w)) * u.w;
  *(float4*)(act + (int64_t)s * ID + i4) = r;
}

// ---------------------------------------------------------------------------
// out[t][h] = w[t,0]*y[2t][h] + w[t,1]*y[2t+1][h]
// ---------------------------------------------------------------------------
__global__ __launch_bounds__(256) void combine_k(const float* __restrict__ y,
                                                 const float* __restrict__ wts,
                                                 float* __restrict__ out) {
  int idx = blockIdx.x * 256 + threadIdx.x;   // < NTOK * HD/4 = 131072
  int t  = idx >> 9;
  int h4 = (idx & 511) << 2;
  float w0 = wts[t * 2], w1 = wts[t * 2 + 1];
  const float4 y0 = *(const float4*)(y + (int64_t)(2 * t) * HD + h4);
  const float4 y1 = *(const float4*)(y + (int64_t)(2 * t + 1) * HD + h4);
  float4 r;
  r.x = w0 * y0.x + w1 * y1.x;
  r.y = w0 * y0.y + w1 * y1.y;
  r.z = w0 * y0.z + w1 * y1.z;
  r.w = w0 * y0.w + w1 * y1.w;
  *(float4*)(out + (int64_t)t * HD + h4) = r;
}

extern "C" void kernel_launch(void* const* d_in, const int* in_sizes, int n_in,
                              void* d_out, int out_size, void* d_ws, size_t ws_size,
                              hipStream_t stream) {
  const float* x   = (const float*)d_in[0];
  const int*   ids = (const int*)d_in[1];
  const float* wts = (const float*)d_in[2];
  const float* w13 = (const float*)d_in[3];
  const float* s13 = (const float*)d_in[4];
  const float* w2  = (const float*)d_in[5];
  const float* s2  = (const float*)d_in[6];
  float* out = (float*)d_out;

  char* ws = (char*)d_ws;
  int* counts = (int*)ws;                                 // 32 B
  int* slots  = (int*)(ws + 64);                          // 16 KiB
  float* gu   = (float*)(ws + 32768);                     // 4 MiB (512 x 2048)
  float* act  = (float*)(ws + 32768 + (4u << 20));        // 2 MiB (512 x 1024)
  float* y    = (float*)(ws + 32768 + (6u << 20));        // 4 MiB (512 x 2048)

  route_k<<<1, 256, 0, stream>>>(ids, counts, slots);

  // GEMM1: gu[slot, n], n in [0, 2I), K = H, A row = x[slot>>1]
  moe_gemm_mfma<HD, 1><<<dim3(32, 8, NEXP), 256, 0, stream>>>(
      x, HD,
      w13, (int64_t)(2 * ID) * HD,
      s13, (2 * ID / 128) * (HD / 128), HD / 128,
      gu, 2 * ID, counts, slots);

  act_k<<<512, 256, 0, stream>>>(gu, act);

  // GEMM2: y[slot, h], h in [0, H), K = I, A row = act[slot]
  moe_gemm_mfma<ID, 0><<<dim3(32, 8, NEXP), 256, 0, stream>>>(
      act, ID,
      w2, (int64_t)HD * ID,
      s2, (HD / 128) * (ID / 128), ID / 128,
      y, HD, counts, slots);

  combine_k<<<512, 256, 0, stream>>>(y, wts, out);
}

// Round 5
// 285.934 us; speedup vs baseline: 2.3766x; 1.1815x over previous
//
#include <hip/hip_runtime.h>
#include <cstdint>

#define NEXP 8
#define NTOK 256
#define NSLOT 512   // NTOK * TOPK
#define HD 2048
#define ID 1024

typedef short bf16x8 __attribute__((ext_vector_type(8)));
typedef float f32x4  __attribute__((ext_vector_type(4)));

// ---------------------------------------------------------------------------
// Routing: per-expert slot lists. slot s = t*2 + k.
// ---------------------------------------------------------------------------
__global__ __launch_bounds__(256) void route_k(const int* __restrict__ ids,
                                               int* __restrict__ counts,
                                               int* __restrict__ slots) {
  int tid = threadIdx.x;
  if (tid < NEXP) counts[tid] = 0;
  __syncthreads();
  for (int s = tid; s < NSLOT; s += 256) {
    int e = ids[s];
    int pos = atomicAdd(&counts[e], 1);
    slots[e * NSLOT + pos] = s;
  }
}

__global__ __launch_bounds__(256) void zero_k(float4* __restrict__ p, int n4) {
  int i = blockIdx.x * 256 + threadIdx.x;
  if (i < n4) p[i] = make_float4(0.f, 0.f, 0.f, 0.f);
}

// split fp32 -> (hi, lo) bf16 pair; hi = truncation, lo = rne(f - hi).
__device__ __forceinline__ void split4(float x, float y, float z, float w,
                                       uint2& hi, uint2& lo) {
  uint32_t u0 = __float_as_uint(x), u1 = __float_as_uint(y),
           u2 = __float_as_uint(z), u3 = __float_as_uint(w);
  uint32_t h0 = u0 & 0xFFFF0000u, h1 = u1 & 0xFFFF0000u;
  uint32_t h2 = u2 & 0xFFFF0000u, h3 = u3 & 0xFFFF0000u;
  hi.x = (u0 >> 16) | h1;
  hi.y = (u2 >> 16) | h3;
  float l0 = x - __uint_as_float(h0), l1 = y - __uint_as_float(h1);
  float l2 = z - __uint_as_float(h2), l3 = w - __uint_as_float(h3);
  lo.x = (__float_as_uint(l0) >> 16) | (__float_as_uint(l1) & 0xFFFF0000u);
  lo.y = (__float_as_uint(l2) >> 16) | (__float_as_uint(l3) & 0xFFFF0000u);
}

// ---------------------------------------------------------------------------
// Grouped GEMM, split-bf16 MFMA, fused block-128 dequant, split-K by KS.
// Partial sums accumulated with fp32 atomicAdd (outputs pre-zeroed).
// FUSE: epilogue adds acc * wts[slot] into C[slot>>1] (fused combine).
// Tile BM=64 x BN=64 x BK=32, 4 waves (2x2), double-buffered LDS,
// rows padded to 40 ushorts (80 B, 16B-aligned -> 2-way banks = free, m136).
// ---------------------------------------------------------------------------
template <int K, int ASHIFT, int KS, bool FUSE>
__global__ __launch_bounds__(256, 3) void moe_gemm_mfma(
    const float* __restrict__ A, int lda,
    const float* __restrict__ B, int64_t bstride,
    const float* __restrict__ Sc, int sstride_e, int sstride_n,
    float* __restrict__ C, int ldc,
    const float* __restrict__ wts,
    const int* __restrict__ counts, const int* __restrict__ slots) {
  constexpr int NT = K / 32;        // K-steps total
  constexpr int NTC = NT / KS;      // K-steps per block (even)
  const int e  = blockIdx.z / KS;
  const int kc = blockIdx.z % KS;
  const int cnt = counts[e];
  const int mbase = blockIdx.y * 64;
  if (mbase >= cnt) return;
  const int n0 = blockIdx.x * 64;
  const int t0 = kc * NTC;

  __shared__ ushort Ah[2][64][40], Al[2][64][40];
  __shared__ ushort Bh[2][64][40], Bl[2][64][40];
  __shared__ int   s_slots[64];
  __shared__ float s_wts[64];

  const int tid = threadIdx.x;
  const int lane = tid & 63;
  const int wave = tid >> 6;
  const int wm = wave >> 1;   // 32-row strip
  const int wn = wave & 1;    // 32-col strip

  const int* sl = slots + e * NSLOT;
  if (tid < 64) {
    int m = mbase + tid;
    int sv = sl[m < cnt ? m : cnt - 1];
    s_slots[tid] = sv;
    s_wts[tid] = FUSE ? wts[sv] : 0.f;
  }

  const int rs = tid >> 3;         // 0..31 staging row
  const int c4 = (tid & 7) << 2;   // 0..28 staging k (floats)

  int ma0 = mbase + rs;      ma0 = ma0 < cnt ? ma0 : cnt - 1;
  int ma1 = mbase + 32 + rs; ma1 = ma1 < cnt ? ma1 : cnt - 1;
  const float* ap0 = A + (int64_t)(sl[ma0] >> ASHIFT) * lda + c4;
  const float* ap1 = A + (int64_t)(sl[ma1] >> ASHIFT) * lda + c4;
  const float* Be  = B + (int64_t)e * bstride;
  const float* bp0 = Be + (int64_t)(n0 + rs) * K + c4;
  const float* bp1 = Be + (int64_t)(n0 + 32 + rs) * K + c4;
  const float* Se  = Sc + e * sstride_e + (n0 >> 7) * sstride_n;

  f32x4 acc[2][2] = {};

  float4 A0a, A1a, B0a, B1a;
  float4 A0b, A1b, B0b, B1b;

#define GLOAD(S, t)                                  \
  {                                                  \
    const int k0_ = (t) * 32;                        \
    A0##S = *(const float4*)(ap0 + k0_);             \
    A1##S = *(const float4*)(ap1 + k0_);             \
    B0##S = *(const float4*)(bp0 + k0_);             \
    B1##S = *(const float4*)(bp1 + k0_);             \
  }

  auto stage = [&](int buf, int tt, const float4& a0, const float4& a1,
                   const float4& b0, const float4& b1) {
    const float s = Se[tt >> 2];   // scale block: 128 floats = 4 K-steps
    uint2 h, l;
    split4(a0.x, a0.y, a0.z, a0.w, h, l);
    *(uint2*)&Ah[buf][rs][c4] = h;       *(uint2*)&Al[buf][rs][c4] = l;
    split4(a1.x, a1.y, a1.z, a1.w, h, l);
    *(uint2*)&Ah[buf][rs + 32][c4] = h;  *(uint2*)&Al[buf][rs + 32][c4] = l;
    split4(b0.x * s, b0.y * s, b0.z * s, b0.w * s, h, l);
    *(uint2*)&Bh[buf][rs][c4] = h;       *(uint2*)&Bl[buf][rs][c4] = l;
    split4(b1.x * s, b1.y * s, b1.z * s, b1.w * s, h, l);
    *(uint2*)&Bh[buf][rs + 32][c4] = h;  *(uint2*)&Bl[buf][rs + 32][c4] = l;
  };

  auto do_mfma = [&](int buf) {
    if (mbase + (wm << 5) >= cnt) return;   // wave-uniform skip
    const int k8 = (lane >> 4) << 3;
    const int ar = (wm << 5) + (lane & 15);
    const int br = (wn << 5) + (lane & 15);
    bf16x8 ah[2], al2[2], bh[2], bl2[2];
#pragma unroll
    for (int i = 0; i < 2; ++i) {
      ah[i]  = *(const bf16x8*)&Ah[buf][ar + i * 16][k8];
      al2[i] = *(const bf16x8*)&Al[buf][ar + i * 16][k8];
      bh[i]  = *(const bf16x8*)&Bh[buf][br + i * 16][k8];
      bl2[i] = *(const bf16x8*)&Bl[buf][br + i * 16][k8];
    }
#pragma unroll
    for (int mf = 0; mf < 2; ++mf)
#pragma unroll
      for (int nf = 0; nf < 2; ++nf) {
        acc[mf][nf] = __builtin_amdgcn_mfma_f32_16x16x32_bf16(ah[mf],  bh[nf],  acc[mf][nf], 0, 0, 0);
        acc[mf][nf] = __builtin_amdgcn_mfma_f32_16x16x32_bf16(ah[mf],  bl2[nf], acc[mf][nf], 0, 0, 0);
        acc[mf][nf] = __builtin_amdgcn_mfma_f32_16x16x32_bf16(al2[mf], bh[nf],  acc[mf][nf], 0, 0, 0);
      }
  };

  GLOAD(a, t0)
  GLOAD(b, t0 + 1)
  stage(0, t0, A0a, A1a, B0a, B1a);
  __syncthreads();

  for (int t = t0; t < t0 + NTC; t += 2) {
    if (t + 2 < t0 + NTC) GLOAD(a, t + 2)
    do_mfma(0);
    stage(1, t + 1, A0b, A1b, B0b, B1b);
    __syncthreads();
    if (t + 3 < t0 + NTC) GLOAD(b, t + 3)
    do_mfma(1);
    if (t + 2 < t0 + NTC) stage(0, t + 2, A0a, A1a, B0a, B1a);
    __syncthreads();
  }
#undef GLOAD

  // epilogue: C/D layout col = lane&15, row = (lane>>4)*4 + reg  [m89]
#pragma unroll
  for (int mf = 0; mf < 2; ++mf) {
#pragma unroll
    for (int nf = 0; nf < 2; ++nf) {
      const int rbase = (wm << 5) + (mf << 4) + ((lane >> 4) << 2);
      const int col = n0 + (wn << 5) + (nf << 4) + (lane & 15);
#pragma unroll
      for (int r = 0; r < 4; ++r) {
        const int row = rbase + r;
        if (mbase + row < cnt) {
          if (FUSE) {
            atomicAdd(&C[(int64_t)(s_slots[row] >> 1) * ldc + col],
                      acc[mf][nf][r] * s_wts[row]);
          } else {
            atomicAdd(&C[(int64_t)s_slots[row] * ldc + col], acc[mf][nf][r]);
          }
        }
      }
    }
  }
}

// ---------------------------------------------------------------------------
// act[s][i] = silu(gu[s][i]) * gu[s][I+i]
// ---------------------------------------------------------------------------
__global__ __launch_bounds__(256) void act_k(const float* __restrict__ gu,
                                             float* __restrict__ act) {
  int idx = blockIdx.x * 256 + threadIdx.x;   // < NSLOT * ID/4 = 131072
  int s  = idx >> 8;
  int i4 = (idx & 255) << 2;
  const float4 g = *(const float4*)(gu + (int64_t)s * (2 * ID) + i4);
  const float4 u = *(const float4*)(gu + (int64_t)s * (2 * ID) + ID + i4);
  float4 r;
  r.x = g.x / (1.f + expf(-g.x)) * u.x;
  r.y = g.y / (1.f + expf(-g.y)) * u.y;
  r.z = g.z / (1.f + expf(-g.z)) * u.z;
  r.w = g.w / (1.f + expf(-g.w)) * u.w;
  *(float4*)(act + (int64_t)s * ID + i4) = r;
}

extern "C" void kernel_launch(void* const* d_in, const int* in_sizes, int n_in,
                              void* d_out, int out_size, void* d_ws, size_t ws_size,
                              hipStream_t stream) {
  const float* x   = (const float*)d_in[0];
  const int*   ids = (const int*)d_in[1];
  const float* wts = (const float*)d_in[2];
  const float* w13 = (const float*)d_in[3];
  const float* s13 = (const float*)d_in[4];
  const float* w2  = (const float*)d_in[5];
  const float* s2  = (const float*)d_in[6];
  float* out = (float*)d_out;

  char* ws = (char*)d_ws;
  int* counts = (int*)ws;                                 // 32 B
  int* slots  = (int*)(ws + 64);                          // 16 KiB
  float* gu   = (float*)(ws + 32768);                     // 4 MiB (512 x 2048)
  float* act  = (float*)(ws + 32768 + (4u << 20));        // 2 MiB (512 x 1024)

  route_k<<<1, 256, 0, stream>>>(ids, counts, slots);
  zero_k<<<1024, 256, 0, stream>>>((float4*)gu, NSLOT * 2 * ID / 4);
  zero_k<<<512, 256, 0, stream>>>((float4*)out, NTOK * HD / 4);

  // GEMM1: gu[slot, n], n in [0, 2I), K = H, A row = x[slot>>1], split-K x4
  moe_gemm_mfma<HD, 1, 4, false><<<dim3(32, 8, NEXP * 4), 256, 0, stream>>>(
      x, HD,
      w13, (int64_t)(2 * ID) * HD,
      s13, (2 * ID / 128) * (HD / 128), HD / 128,
      gu, 2 * ID, nullptr, counts, slots);

  act_k<<<512, 256, 0, stream>>>(gu, act);

  // GEMM2 fused with combine: out[slot>>1, h] += y * wts[slot], split-K x4
  moe_gemm_mfma<ID, 0, 4, true><<<dim3(32, 8, NEXP * 4), 256, 0, stream>>>(
      act, ID,
      w2, (int64_t)HD * ID,
      s2, (HD / 128) * (ID / 128), ID / 128,
      out, HD, wts, counts, slots);
}

// Round 7
// 282.172 us; speedup vs baseline: 2.4083x; 1.0133x over previous
//
#include <hip/hip_runtime.h>
#include <cstdint>

#define NEXP 8
#define NTOK 256
#define NSLOT 512   // NTOK * TOPK
#define HD 2048
#define ID 1024

typedef short bf16x8 __attribute__((ext_vector_type(8)));
typedef float f32x4  __attribute__((ext_vector_type(4)));

// ---------------------------------------------------------------------------
// Routing: per-expert slot lists. slot s = t*2 + k.
// ---------------------------------------------------------------------------
__global__ __launch_bounds__(256) void route_k(const int* __restrict__ ids,
                                               int* __restrict__ counts,
                                               int* __restrict__ slots) {
  int tid = threadIdx.x;
  if (tid < NEXP) counts[tid] = 0;
  __syncthreads();
  for (int s = tid; s < NSLOT; s += 256) {
    int e = ids[s];
    int pos = atomicAdd(&counts[e], 1);
    slots[e * NSLOT + pos] = s;
  }
}

// split fp32 -> (hi, lo) bf16 pair; hi = truncation, lo = rne(f - hi).
__device__ __forceinline__ void split4(float x, float y, float z, float w,
                                       uint2& hi, uint2& lo) {
  uint32_t u0 = __float_as_uint(x), u1 = __float_as_uint(y),
           u2 = __float_as_uint(z), u3 = __float_as_uint(w);
  uint32_t h0 = u0 & 0xFFFF0000u, h1 = u1 & 0xFFFF0000u;
  uint32_t h2 = u2 & 0xFFFF0000u, h3 = u3 & 0xFFFF0000u;
  hi.x = (u0 >> 16) | h1;
  hi.y = (u2 >> 16) | h3;
  float l0 = x - __uint_as_float(h0), l1 = y - __uint_as_float(h1);
  float l2 = z - __uint_as_float(h2), l3 = w - __uint_as_float(h3);
  lo.x = (__float_as_uint(l0) >> 16) | (__float_as_uint(l1) & 0xFFFF0000u);
  lo.y = (__float_as_uint(l2) >> 16) | (__float_as_uint(l3) & 0xFFFF0000u);
}

// ---------------------------------------------------------------------------
// Grouped GEMM body, split-bf16 MFMA, fused block-128 dequant, split-K by KS.
// Writes per-chunk partials: Cpart[kc][slot][ldc] (no atomics).
// Tile BM=64 x BN=64 x BK=32, 4 waves (2x2).
// Schedule: minimum 2-phase (T3/T4-lite): fully unrolled K-loop, ONE raw
// s_barrier per K-step (read cur buf -> write next buf -> lgkmcnt(0)+barrier),
// global loads issued a full step before their split/ds_write consumption so
// they stay in flight ACROSS the barrier (no vmcnt(0) drain).
// ---------------------------------------------------------------------------
template <int K, int ASHIFT, int KS>
__device__ __forceinline__ void gemm_body(
    const float* __restrict__ A, int lda,
    const float* __restrict__ B, int64_t bstride,
    const float* __restrict__ Sc, int sstride_e, int sstride_n,
    float* __restrict__ C, int ldc,
    const int* __restrict__ counts, const int* __restrict__ slots) {
  constexpr int NT = K / 32;        // K-steps total
  constexpr int NTC = NT / KS;      // K-steps per chunk
  constexpr int NSC = NTC / 4;      // scale blocks per chunk (128 = 4 steps)
  const int e  = blockIdx.z / KS;
  const int kc = blockIdx.z % KS;
  const int cnt = counts[e];
  const int mbase = blockIdx.y * 64;
  if (mbase >= cnt) return;
  const int n0 = blockIdx.x * 64;
  const int t0 = kc * NTC;
  float* Cpart = C + (int64_t)kc * NSLOT * ldc;

  __shared__ ushort Ah[2][64][40], Al[2][64][40];  // 80 B rows: 2-way banks
  __shared__ ushort Bh[2][64][40], Bl[2][64][40];
  __shared__ int s_slots[64];

  const int tid = threadIdx.x;
  const int lane = tid & 63;
  const int wave = tid >> 6;
  const int wm = wave >> 1;   // 32-row strip
  const int wn = wave & 1;    // 32-col strip

  const int* sl = slots + e * NSLOT;
  if (tid < 64) {
    int m = mbase + tid;
    s_slots[tid] = sl[m < cnt ? m : cnt - 1];
  }

  const int rs = tid >> 3;         // 0..31 staging row
  const int c4 = (tid & 7) << 2;   // 0..28 staging k (floats)

  int ma0 = mbase + rs;      ma0 = ma0 < cnt ? ma0 : cnt - 1;
  int ma1 = mbase + 32 + rs; ma1 = ma1 < cnt ? ma1 : cnt - 1;
  const float* ap0 = A + (int64_t)(sl[ma0] >> ASHIFT) * lda + t0 * 32 + c4;
  const float* ap1 = A + (int64_t)(sl[ma1] >> ASHIFT) * lda + t0 * 32 + c4;
  const float* Be  = B + (int64_t)e * bstride;
  const float* bp0 = Be + (int64_t)(n0 + rs) * K + t0 * 32 + c4;
  const float* bp1 = Be + (int64_t)(n0 + 32 + rs) * K + t0 * 32 + c4;

  // preload chunk's dequant scales (uniform -> SGPR; no vector loads in loop)
  float scl[NSC];
  {
    const float* Se = Sc + e * sstride_e + (n0 >> 7) * sstride_n + kc * NSC;
#pragma unroll
    for (int i = 0; i < NSC; ++i) scl[i] = Se[i];
  }

  f32x4 acc[2][2] = {};
  float4 rA0[2], rA1[2], rB0[2], rB1[2];   // two prefetch sets (parity t&1)

  auto gload = [&](int s, int t) {
    rA0[s] = *(const float4*)(ap0 + t * 32);
    rA1[s] = *(const float4*)(ap1 + t * 32);
    rB0[s] = *(const float4*)(bp0 + t * 32);
    rB1[s] = *(const float4*)(bp1 + t * 32);
  };

  auto stage_s = [&](int s, int buf, float sc) {
    uint2 h, l;
    split4(rA0[s].x, rA0[s].y, rA0[s].z, rA0[s].w, h, l);
    *(uint2*)&Ah[buf][rs][c4] = h;       *(uint2*)&Al[buf][rs][c4] = l;
    split4(rA1[s].x, rA1[s].y, rA1[s].z, rA1[s].w, h, l);
    *(uint2*)&Ah[buf][rs + 32][c4] = h;  *(uint2*)&Al[buf][rs + 32][c4] = l;
    split4(rB0[s].x * sc, rB0[s].y * sc, rB0[s].z * sc, rB0[s].w * sc, h, l);
    *(uint2*)&Bh[buf][rs][c4] = h;       *(uint2*)&Bl[buf][rs][c4] = l;
    split4(rB1[s].x * sc, rB1[s].y * sc, rB1[s].z * sc, rB1[s].w * sc, h, l);
    *(uint2*)&Bh[buf][rs + 32][c4] = h;  *(uint2*)&Bl[buf][rs + 32][c4] = l;
  };

  auto mfma_step = [&](int buf) {
    if (mbase + (wm << 5) >= cnt) return;   // wave-uniform skip
    const int k8 = (lane >> 4) << 3;
    const int ar = (wm << 5) + (lane & 15);
    const int br = (wn << 5) + (lane & 15);
    bf16x8 ah[2], al2[2], bh[2], bl2[2];
#pragma unroll
    for (int i = 0; i < 2; ++i) {
      ah[i]  = *(const bf16x8*)&Ah[buf][ar + i * 16][k8];
      al2[i] = *(const bf16x8*)&Al[buf][ar + i * 16][k8];
      bh[i]  = *(const bf16x8*)&Bh[buf][br + i * 16][k8];
      bl2[i] = *(const bf16x8*)&Bl[buf][br + i * 16][k8];
    }
#pragma unroll
    for (int mf = 0; mf < 2; ++mf)
#pragma unroll
      for (int nf = 0; nf < 2; ++nf) {
        acc[mf][nf] = __builtin_amdgcn_mfma_f32_16x16x32_bf16(ah[mf],  bh[nf],  acc[mf][nf], 0, 0, 0);
        acc[mf][nf] = __builtin_amdgcn_mfma_f32_16x16x32_bf16(ah[mf],  bl2[nf], acc[mf][nf], 0, 0, 0);
        acc[mf][nf] = __builtin_amdgcn_mfma_f32_16x16x32_bf16(al2[mf], bh[nf],  acc[mf][nf], 0, 0, 0);
      }
  };

  // prologue: load sets 0,1; stage step 0 into buf 0; barrier (covers s_slots)
  gload(0, 0);
  gload(1, 1);
  stage_s(0, 0, scl[0]);
  asm volatile("s_waitcnt lgkmcnt(0)" ::: "memory");
  __builtin_amdgcn_s_barrier();

#pragma unroll
  for (int t = 0; t < NTC; ++t) {
    const int buf = t & 1;
    if (t + 2 < NTC) gload(buf, t + 2);       // stays in flight across barrier
    mfma_step(buf);
    if (t + 1 < NTC) {
      stage_s((t + 1) & 1, (t + 1) & 1, scl[(t + 1) >> 2]);
      asm volatile("s_waitcnt lgkmcnt(0)" ::: "memory");
      __builtin_amdgcn_s_barrier();
    }
  }

  // epilogue: C/D layout col = lane&15, row = (lane>>4)*4 + reg  [m89]
#pragma unroll
  for (int mf = 0; mf < 2; ++mf) {
#pragma unroll
    for (int nf = 0; nf < 2; ++nf) {
      const int rbase = (wm << 5) + (mf << 4) + ((lane >> 4) << 2);
      const int col = n0 + (wn << 5) + (nf << 4) + (lane & 15);
#pragma unroll
      for (int r = 0; r < 4; ++r) {
        const int row = rbase + r;
        if (mbase + row < cnt)
          Cpart[(int64_t)s_slots[row] * ldc + col] = acc[mf][nf][r];
      }
    }
  }
}

__global__ __launch_bounds__(256, 3) void gemm1_k(
    const float* __restrict__ A, const float* __restrict__ B,
    const float* __restrict__ Sc, float* __restrict__ C,
    const int* __restrict__ counts, const int* __restrict__ slots) {
  gemm_body<HD, 1, 4>(A, HD, B, (int64_t)(2 * ID) * HD,
                      Sc, (2 * ID / 128) * (HD / 128), HD / 128,
                      C, 2 * ID, counts, slots);
}

__global__ __launch_bounds__(256, 3) void gemm2_k(
    const float* __restrict__ A, const float* __restrict__ B,
    const float* __restrict__ Sc, float* __restrict__ C,
    const int* __restrict__ counts, const int* __restrict__ slots) {
  gemm_body<ID, 0, 4>(A, ID, B, (int64_t)HD * ID,
                      Sc, (HD / 128) * (ID / 128), ID / 128,
                      C, HD, counts, slots);
}

// ---------------------------------------------------------------------------
// act[s][i] = silu(sum_kc gu_part[kc][s][i]) * (sum_kc gu_part[kc][s][I+i])
// ---------------------------------------------------------------------------
__global__ __launch_bounds__(256) void act_k(const float* __restrict__ gup,
                                             float* __restrict__ act) {
  int idx = blockIdx.x * 256 + threadIdx.x;   // < NSLOT * ID/4 = 131072
  int s  = idx >> 8;
  int i4 = (idx & 255) << 2;
  float4 g = make_float4(0.f, 0.f, 0.f, 0.f);
  float4 u = make_float4(0.f, 0.f, 0.f, 0.f);
#pragma unroll
  for (int kc = 0; kc < 4; ++kc) {
    const float* p = gup + ((int64_t)kc * NSLOT + s) * (2 * ID);
    const float4 gv = *(const float4*)(p + i4);
    const float4 uv = *(const float4*)(p + ID + i4);
    g.x += gv.x; g.y += gv.y; g.z += gv.z; g.w += gv.w;
    u.x += uv.x; u.y += uv.y; u.z += uv.z; u.w += uv.w;
  }
  float4 r;
  r.x = g.x / (1.f + expf(-g.x)) * u.x;
  r.y = g.y / (1.f + expf(-g.y)) * u.y;
  r.z = g.z / (1.f + expf(-g.z)) * u.z;
  r.w = g.w / (1.f + expf(-g.w)) * u.w;
  *(float4*)(act + (int64_t)s * ID + i4) = r;
}

// ---------------------------------------------------------------------------
// out[t][h] = w[t,0]*sum_kc yp[kc][2t][h] + w[t,1]*sum_kc yp[kc][2t+1][h]
// ---------------------------------------------------------------------------
__global__ __launch_bounds__(256) void combine_k(const float* __restrict__ yp,
                                                 const float* __restrict__ wts,
                                                 float* __restrict__ out) {
  int idx = blockIdx.x * 256 + threadIdx.x;   // < NTOK * HD/4 = 131072
  int t  = idx >> 9;
  int h4 = (idx & 511) << 2;
  float w0 = wts[t * 2], w1 = wts[t * 2 + 1];
  float4 y0 = make_float4(0.f, 0.f, 0.f, 0.f);
  float4 y1 = make_float4(0.f, 0.f, 0.f, 0.f);
#pragma unroll
  for (int kc = 0; kc < 4; ++kc) {
    const float* p0 = yp + ((int64_t)kc * NSLOT + 2 * t) * HD;
    const float4 a = *(const float4*)(p0 + h4);
    const float4 b = *(const float4*)(p0 + HD + h4);
    y0.x += a.x; y0.y += a.y; y0.z += a.z; y0.w += a.w;
    y1.x += b.x; y1.y += b.y; y1.z += b.z; y1.w += b.w;
  }
  float4 r;
  r.x = w0 * y0.x + w1 * y1.x;
  r.y = w0 * y0.y + w1 * y1.y;
  r.z = w0 * y0.z + w1 * y1.z;
  r.w = w0 * y0.w + w1 * y1.w;
  *(float4*)(out + (int64_t)t * HD + h4) = r;
}

extern "C" void kernel_launch(void* const* d_in, const int* in_sizes, int n_in,
                              void* d_out, int out_size, void* d_ws, size_t ws_size,
                              hipStream_t stream) {
  const float* x   = (const float*)d_in[0];
  const int*   ids = (const int*)d_in[1];
  const float* wts = (const float*)d_in[2];
  const float* w13 = (const float*)d_in[3];
  const float* s13 = (const float*)d_in[4];
  const float* w2  = (const float*)d_in[5];
  const float* s2  = (const float*)d_in[6];
  float* out = (float*)d_out;

  char* ws = (char*)d_ws;
  int* counts    = (int*)ws;                                  // 32 B
  int* slots     = (int*)(ws + 64);                           // 16 KiB
  float* gu_part = (float*)(ws + 32768);                      // 16 MiB (4 x 512 x 2048)
  float* act     = (float*)(ws + 32768 + (16u << 20));        // 2 MiB  (512 x 1024)
  float* y_part  = (float*)(ws + 32768 + (18u << 20));        // 16 MiB (4 x 512 x 2048)

  route_k<<<1, 256, 0, stream>>>(ids, counts, slots);

  // GEMM1: gu_part[kc][slot, n], n in [0, 2I), K = H, A row = x[slot>>1]
  gemm1_k<<<dim3(32, 8, NEXP * 4), 256, 0, stream>>>(
      x, w13, s13, gu_part, counts, slots);

  act_k<<<512, 256, 0, stream>>>(gu_part, act);

  // GEMM2: y_part[kc][slot, h], h in [0, H), K = I, A row = act[slot]
  gemm2_k<<<dim3(32, 8, NEXP * 4), 256, 0, stream>>>(
      act, w2, s2, y_part, counts, slots);

  combine_k<<<512, 256, 0, stream>>>(y_part, wts, out);
}